// Round 13
// baseline (302.661 us; speedup 1.0000x reference)
//
// v14 — r12 (300.7us best) + gemm staging rewritten with global_load_lds(16B)
// and st-16x32-style XOR swizzle (linear LDS dest + pre-swizzled global src +
// swizzled ds_read; rule #21 both-sides-or-neither). Budget arithmetic says the
// gemms are ~40-50us each (naive-staging tier, 73 GF); m97 recipe targets that.
// Data in LDS identical -> bit-identical outputs. All else = r12.
#include <hip/hip_runtime.h>
#include <hip/hip_bf16.h>
#include <cstdint>

#define N_NODES 50000
#define N_EDGES 800000
#define ET_EDGES (N_EDGES + N_NODES)   // with self-loops
#define FDIM 256
#define BN_EPS 1e-5f
#define CAP 96                         // fixed CSR slots per node; P(deg>96)~0 for Poisson(17)

typedef short bf16x8 __attribute__((ext_vector_type(8)));   // 8 bf16 = 4 VGPRs
typedef float f32x4 __attribute__((ext_vector_type(4)));

__device__ __forceinline__ float lrelu(float x) { return x >= 0.f ? x : 0.2f * x; }
__device__ __forceinline__ unsigned short f2b(float f) {   // RNE
    unsigned int u = __float_as_uint(f);
    u += 0x7fffu + ((u >> 16) & 1u);
    return (unsigned short)(u >> 16);
}

// async global->LDS, 16B per lane; LDS dest is wave-uniform base + lane*16
__device__ __forceinline__ void gload16(const void* gsrc, void* ldst) {
    __builtin_amdgcn_global_load_lds(
        (const __attribute__((address_space(1))) void*)gsrc,
        (__attribute__((address_space(3))) void*)ldst, 16, 0, 0);
}

// u8 (biased int8: q+128) dequant-accumulate: 8 features from an int2, coefficient c.
// (float)(unsigned char)(x>>8k) selects v_cvt_f32_ubyte0..3 — 1 inst/byte vs bfe+cvt.
// The +128 bias is removed once per node: acc -= 128 * sum(alpha*scale).
__device__ __forceinline__ void acc_u8(float acc8[8], int2 p, float c) {
    unsigned px = (unsigned)p.x, py = (unsigned)p.y;
#pragma unroll
    for (int k = 0; k < 4; ++k)
        acc8[k] = fmaf((float)((unsigned char)(px >> (8 * k))), c, acc8[k]);
#pragma unroll
    for (int k = 0; k < 4; ++k)
        acc8[k + 4] = fmaf((float)((unsigned char)(py >> (8 * k))), c, acc8[k + 4]);
}

// ------- fused setup+scatter: interleaved 1:1 (both 0 LDS -> full occupancy;
//         setup = HBM/VALU-bound, scatter = atomic-unit-bound -> true overlap) -------
#define NB_CONV2 3125           // 50000*128/4 float4s / 512 (2 float4 per thread)
#define NB_WT1  128             // 256*128 / 256
#define NB_WT2  256             // 256*256 / 256
#define SETUP_B (NB_CONV2 + NB_WT1 + NB_WT2 + 1)   // 3510
#define SCAT_B  3321            // ceil(850000/256), 1 edge per thread
__global__ __launch_bounds__(256) void setup_scatter_kernel(
        const float* __restrict__ x, unsigned short* __restrict__ xb,
        const float* __restrict__ W1, unsigned short* __restrict__ W1T,
        const float* __restrict__ W2, unsigned short* __restrict__ W2T,
        const int* __restrict__ ei, int* __restrict__ cursor, int* __restrict__ csr,
        const float* __restrict__ b1, const float* __restrict__ g1,
        const float* __restrict__ be1, const float* __restrict__ m1,
        const float* __restrict__ v1,
        const float* __restrict__ b2, const float* __restrict__ g2,
        const float* __restrict__ be2, const float* __restrict__ m2,
        const float* __restrict__ v2,
        float* sc1, float* sh1, float* sc2, float* sh2) {
    int b = blockIdx.x, tid = threadIdx.x;
    if (b < 2 * SCAT_B && (b & 1)) {
        // ---- scatter block: 1 edge/thread, latency hidden via occupancy ----
        int e = (b >> 1) * 256 + tid;
        if (e >= ET_EDGES) return;
        int s, d;
        if (e < N_EDGES) { s = ei[e]; d = ei[N_EDGES + e]; }
        else             { s = d = e - N_EDGES; }
        int pos = atomicAdd(&cursor[d], 1);
        if (pos < CAP) csr[d * CAP + pos] = s;
        return;
    }
    int sb = (b < 2 * SCAT_B) ? (b >> 1) : (b - SCAT_B);   // logical setup block id
    if (sb < NB_CONV2) {
        int i = sb * 512 + tid;
#pragma unroll
        for (int u = 0; u < 2; ++u, i += 256) {
            float4 v = ((const float4*)x)[i];
            ushort4 o;
            o.x = f2b(v.x); o.y = f2b(v.y); o.z = f2b(v.z); o.w = f2b(v.w);
            ((ushort4*)xb)[i] = o;
        }
    } else if (sb < NB_CONV2 + NB_WT1) {
        int t = (sb - NB_CONV2) * 256 + tid;          // over 256*128
        int n = t >> 7, k = t & 127;
        W1T[t] = f2b(W1[(size_t)k * 256 + n]);
    } else if (sb < NB_CONV2 + NB_WT1 + NB_WT2) {
        int t = (sb - NB_CONV2 - NB_WT1) * 256 + tid; // over 256*256
        int n = t >> 8, k = t & 255;
        W2T[t] = f2b(W2[(size_t)k * 256 + n]);
    } else {
        int f = tid;
        float s1 = rsqrtf(v1[f] + BN_EPS) * g1[f];
        sc1[f] = s1;
        sh1[f] = (b1[f] - m1[f]) * s1 + be1[f];
        float s2 = rsqrtf(v2[f] + BN_EPS) * g2[f];
        sc2[f] = s2;
        sh2[f] = (b2[f] - m2[f]) * s2 + be2[f];
    }
}

// ------- bf16 MFMA GEMM 64x256 tile (4 waves, 256 thr) + u8-quant + fused adot.
// Staging: global_load_lds 16B/lane into LINEAR LDS; global source pre-swizzled
// chunk^=(row&7); fragment reads apply the same XOR -> conflict-free, and LDS
// holds identical VALUES to the padded version -> bit-identical results. -------
template <int K>
__global__ __launch_bounds__(256) void gemm_fused_kernel(
        const unsigned short* __restrict__ A,
        const unsigned short* __restrict__ BT,
        const float* __restrict__ a_src, const float* __restrict__ a_dst,
        signed char* __restrict__ H8, float* __restrict__ scaleRow,
        float* __restrict__ asrc, float* __restrict__ adst, int M) {
    constexpr int BK = 64;                        // 64 shorts = 8 chunks of 8
    __shared__ unsigned short AsLin[64 * 64];     // 8 KB, linear
    __shared__ unsigned short BsLin[256 * 64];    // 32 KB, linear
    __shared__ int amaxL[64];                     // per-row |h| max (as ordered int)
    const int tid = threadIdx.x;
    const int lane = tid & 63;
    const int w = tid >> 6;          // 0..3
    const int bm = blockIdx.x * 64;
    const int wc = w * 64;
    const int hd = w;
    if (tid < 64) amaxL[tid] = 0;                 // visible after first K-loop barrier

    f32x4 acc[4][4];
#pragma unroll
    for (int i = 0; i < 4; ++i)
#pragma unroll
        for (int j = 0; j < 4; ++j) acc[i][j] = (f32x4){0.f, 0.f, 0.f, 0.f};

    const int lrow8 = lane >> 3;     // row within an 8-row staging group (0..7)
    const int lch   = lane & 7;      // 16B chunk within row (0..7)
    const int gchA  = lch ^ lrow8;   // pre-swizzled source chunk (row&7 == lrow8)

    for (int k0 = 0; k0 < K; k0 += BK) {
        // ---- A: 2 x 1KB per wave (rows (w*2+c)*8 .. +7) ----
#pragma unroll
        for (int c = 0; c < 2; ++c) {
            int r0 = (w * 2 + c) * 8;
            int ar = bm + r0 + lrow8; if (ar >= M) ar = M - 1;
            gload16(A + (size_t)ar * K + k0 + gchA * 8, &AsLin[r0 * 64]);
        }
        // ---- B: 8 x 1KB per wave (rows w*64 + c*8 .. +7) ----
#pragma unroll
        for (int c = 0; c < 8; ++c) {
            int r0 = w * 64 + c * 8;
            gload16(BT + (size_t)(r0 + lrow8) * K + k0 + gchA * 8, &BsLin[r0 * 64]);
        }
        __syncthreads();              // drains vmcnt -> LDS tile complete
#pragma unroll
        for (int ks = 0; ks < BK; ks += 32) {
            const int c16 = lane & 15;
            const int kc = (ks >> 3) + (lane >> 4);   // chunk index of this lane's 8 shorts
            const int sw = kc ^ (c16 & 7);            // swizzled chunk (row&7 == c16&7)
            bf16x8 af[4], bfr[4];
#pragma unroll
            for (int i = 0; i < 4; ++i) {
                int Ra = i * 16 + c16;
                af[i]  = *(const bf16x8*)&AsLin[Ra * 64 + (sw << 3)];
                int Rb = wc + i * 16 + c16;
                bfr[i] = *(const bf16x8*)&BsLin[Rb * 64 + (sw << 3)];
            }
#pragma unroll
            for (int i = 0; i < 4; ++i)
#pragma unroll
                for (int j = 0; j < 4; ++j)
                    acc[i][j] = __builtin_amdgcn_mfma_f32_16x16x32_bf16(af[i], bfr[j], acc[i][j], 0, 0, 0);
        }
        __syncthreads();
    }

    const int q = lane >> 4, c16 = lane & 15;
    // ---- per-row amax across the 4 column-waves ----
#pragma unroll
    for (int i = 0; i < 4; ++i) {
#pragma unroll
        for (int r = 0; r < 4; ++r) {
            float a = fmaxf(fmaxf(fabsf(acc[i][0][r]), fabsf(acc[i][1][r])),
                            fmaxf(fabsf(acc[i][2][r]), fabsf(acc[i][3][r])));
#pragma unroll
            for (int off = 1; off < 16; off <<= 1) a = fmaxf(a, __shfl_xor(a, off));
            if (c16 == 0) atomicMax(&amaxL[i * 16 + q * 4 + r], __float_as_int(a));
        }
    }
    __syncthreads();

    // ---- quantize + store biased u8 H, row scale, and fused attention dots ----
    float asv[4], adv[4];
#pragma unroll
    for (int j = 0; j < 4; ++j) {
        int c = j * 16 + c16;
        asv[j] = a_src[hd * 64 + c];
        adv[j] = a_dst[hd * 64 + c];
    }
#pragma unroll
    for (int i = 0; i < 4; ++i) {
#pragma unroll
        for (int r = 0; r < 4; ++r) {
            int lrow = i * 16 + q * 4 + r;
            int gr = bm + lrow;
            float amax = __int_as_float(amaxL[lrow]);
            float rcpS = amax > 1e-20f ? 127.f / amax : 0.f;
            if (gr < M) {
#pragma unroll
                for (int j = 0; j < 4; ++j) {
                    int qv = (int)rintf(acc[i][j][r] * rcpS);
                    // biased: store q+128 so the gather can use v_cvt_f32_ubyte
                    H8[(size_t)gr * 256 + wc + j * 16 + c16] =
                        (signed char)(unsigned char)(qv + 128);
                }
                if (c16 == 0 && w == 0) scaleRow[gr] = amax * (1.f / 127.f);
            }
            float p_s = acc[i][0][r] * asv[0] + acc[i][1][r] * asv[1]
                      + acc[i][2][r] * asv[2] + acc[i][3][r] * asv[3];
            float p_d = acc[i][0][r] * adv[0] + acc[i][1][r] * adv[1]
                      + acc[i][2][r] * adv[2] + acc[i][3][r] * adv[3];
#pragma unroll
            for (int off = 1; off < 16; off <<= 1) {
                p_s += __shfl_xor(p_s, off);
                p_d += __shfl_xor(p_d, off);
            }
            if (c16 == 0 && gr < M) {
                asrc[(size_t)gr * 4 + hd] = p_s;
                adst[(size_t)gr * 4 + hd] = p_d;
            }
        }
    }
}

// ---- shared epilogue: BN + ReLU (+ log_softmax over a 32-lane group) ----
template <bool FINAL>
__device__ __forceinline__ void gat_epilogue(const float acc8[8], int fl, bool doStore,
                                             int node, const float* __restrict__ scale,
                                             const float* __restrict__ shift,
                                             float* __restrict__ outf,
                                             unsigned short* __restrict__ outb) {
    float4 scA = ((const float4*)scale)[fl * 2], scB = ((const float4*)scale)[fl * 2 + 1];
    float4 shA = ((const float4*)shift)[fl * 2], shB = ((const float4*)shift)[fl * 2 + 1];
    float t[8];
    t[0] = fmaxf(fmaf(acc8[0], scA.x, shA.x), 0.f);
    t[1] = fmaxf(fmaf(acc8[1], scA.y, shA.y), 0.f);
    t[2] = fmaxf(fmaf(acc8[2], scA.z, shA.z), 0.f);
    t[3] = fmaxf(fmaf(acc8[3], scA.w, shA.w), 0.f);
    t[4] = fmaxf(fmaf(acc8[4], scB.x, shB.x), 0.f);
    t[5] = fmaxf(fmaf(acc8[5], scB.y, shB.y), 0.f);
    t[6] = fmaxf(fmaf(acc8[6], scB.z, shB.z), 0.f);
    t[7] = fmaxf(fmaf(acc8[7], scB.w, shB.w), 0.f);
    if (FINAL) {
        float m = t[0];
#pragma unroll
        for (int k = 1; k < 8; ++k) m = fmaxf(m, t[k]);
#pragma unroll
        for (int off = 1; off < 32; off <<= 1) m = fmaxf(m, __shfl_xor(m, off));
        float es = 0.f;
#pragma unroll
        for (int k = 0; k < 8; ++k) es += __expf(t[k] - m);
#pragma unroll
        for (int off = 1; off < 32; off <<= 1) es += __shfl_xor(es, off);
        float lse = m + logf(es);
        if (doStore) {
            float* p = outf + (size_t)node * 256 + fl * 8;
            *(float4*)p = make_float4(t[0] - lse, t[1] - lse, t[2] - lse, t[3] - lse);
            *(float4*)(p + 4) = make_float4(t[4] - lse, t[5] - lse, t[6] - lse, t[7] - lse);
        }
    } else {
        if (doStore) {
            bf16x8 ob;
#pragma unroll
            for (int k = 0; k < 8; ++k) ob[k] = (short)f2b(t[k]);
            *(bf16x8*)(outb + (size_t)node * 256 + fl * 8) = ob;
        }
    }
}

// ------- fused gather (r7 exact): one-shot 8-node blocks, u8 payload + cvt_ubyte
//         dequant, packed {src,alpha} ds_read_b64, 2 nodes/wave, 8 edges in flight -------
template <bool FINAL>
__global__ __launch_bounds__(256) void gat_gather_kernel(
        const int* __restrict__ cursor,
        const int* __restrict__ csr,
        const float* __restrict__ asrc,
        const float* __restrict__ adst,
        const float* __restrict__ scaleRow,
        const signed char* __restrict__ h8,
        const float* __restrict__ scale,
        const float* __restrict__ shift,
        float* __restrict__ outf,
        unsigned short* __restrict__ outb) {
    // [wave][head][slot] = {src, alpha*scale}; 65 pad -> head arrays 2 banks apart
    __shared__ int2 sa[4][4][65];

    const int wid = threadIdx.x >> 6;
    const int lane = threadIdx.x & 63;
    const int g = lane >> 5, l32 = lane & 31;
    const int hsel = l32 >> 3;
    const unsigned fo = (unsigned)(l32 << 3);   // byte offset of this lane's 8 features

    const int nodeBase = blockIdx.x * 8 + wid * 2;
    if (nodeBase >= N_NODES) return;

    {
        int node = nodeBase + g;
        bool valid = node < N_NODES;
        int nodeC = valid ? node : N_NODES - 1;
        int deg = valid ? min(cursor[nodeC], CAP) : 0;
        int beg = nodeC * CAP;
        int dmax = max(deg, __shfl_xor(deg, 32));

        if (dmax <= 32) {
            // ======== fast path: 32-lane group per node ========
            float4 ad = *(const float4*)(adst + (size_t)nodeC * 4);
            int s = 0;
            float sc = 0.f;
            float c0 = -3.4e38f, c1 = -3.4e38f, c2 = -3.4e38f, c3 = -3.4e38f;
            if (l32 < deg) {
                s = csr[beg + l32];
                sc = scaleRow[s];
                float4 as = *(const float4*)(asrc + (size_t)s * 4);
                c0 = lrelu(as.x + ad.x); c1 = lrelu(as.y + ad.y);
                c2 = lrelu(as.z + ad.z); c3 = lrelu(as.w + ad.w);
            }
            float m0 = c0, m1 = c1, m2 = c2, m3 = c3;
#pragma unroll
            for (int off = 1; off < 32; off <<= 1) {
                m0 = fmaxf(m0, __shfl_xor(m0, off)); m1 = fmaxf(m1, __shfl_xor(m1, off));
                m2 = fmaxf(m2, __shfl_xor(m2, off)); m3 = fmaxf(m3, __shfl_xor(m3, off));
            }
            float e0 = 0.f, e1 = 0.f, e2 = 0.f, e3 = 0.f;
            if (l32 < deg) {
                e0 = __expf(c0 - m0); e1 = __expf(c1 - m1);
                e2 = __expf(c2 - m2); e3 = __expf(c3 - m3);
            }
            float s0 = e0, s1 = e1, s2 = e2, s3 = e3;
#pragma unroll
            for (int off = 1; off < 32; off <<= 1) {
                s0 += __shfl_xor(s0, off); s1 += __shfl_xor(s1, off);
                s2 += __shfl_xor(s2, off); s3 += __shfl_xor(s3, off);
            }
            float a0 = e0 / (s0 + 1e-16f) * sc, a1 = e1 / (s1 + 1e-16f) * sc;
            float a2 = e2 / (s2 + 1e-16f) * sc, a3 = e3 / (s3 + 1e-16f) * sc;
            sa[wid][0][lane] = make_int2(s, __float_as_int(a0));   // slot == lane
            sa[wid][1][lane] = make_int2(s, __float_as_int(a1));
            sa[wid][2][lane] = make_int2(s, __float_as_int(a2));
            sa[wid][3][lane] = make_int2(s, __float_as_int(a3));
            // asum = sum(alpha*scale) per head, for the u8 bias correction
            float t0 = a0, t1 = a1, t2 = a2, t3 = a3;
#pragma unroll
            for (int off = 1; off < 32; off <<= 1) {
                t0 += __shfl_xor(t0, off); t1 += __shfl_xor(t1, off);
                t2 += __shfl_xor(t2, off); t3 += __shfl_xor(t3, off);
            }
            float corr = 128.f * (hsel == 0 ? t0 : hsel == 1 ? t1 : hsel == 2 ? t2 : t3);
            __asm__ volatile("s_waitcnt lgkmcnt(0)" ::: "memory");  // wave-local LDS RAW

            const int2* sal = &sa[wid][hsel][g * 32];
            float acc8[8];
#pragma unroll
            for (int k = 0; k < 8; ++k) acc8[k] = 0.f;

            int e = 0;
            for (; e + 7 < deg; e += 8) {               // 8 loads in flight
                int2 sv[8]; int2 hv[8];
#pragma unroll
                for (int u = 0; u < 8; ++u) sv[u] = sal[e + u];    // ds_read_b64
#pragma unroll
                for (int u = 0; u < 8; ++u)
                    hv[u] = *(const int2*)(h8 + (((unsigned)sv[u].x << 8) + fo));
#pragma unroll
                for (int u = 0; u < 8; ++u) acc_u8(acc8, hv[u], __int_as_float(sv[u].y));
            }
            for (; e + 3 < deg; e += 4) {
                int2 sv[4]; int2 hv[4];
#pragma unroll
                for (int u = 0; u < 4; ++u) sv[u] = sal[e + u];
#pragma unroll
                for (int u = 0; u < 4; ++u)
                    hv[u] = *(const int2*)(h8 + (((unsigned)sv[u].x << 8) + fo));
#pragma unroll
                for (int u = 0; u < 4; ++u) acc_u8(acc8, hv[u], __int_as_float(sv[u].y));
            }
            for (; e < deg; ++e) {
                int2 sv = sal[e];
                int2 hA = *(const int2*)(h8 + (((unsigned)sv.x << 8) + fo));
                acc_u8(acc8, hA, __int_as_float(sv.y));
            }
#pragma unroll
            for (int k = 0; k < 8; ++k) acc8[k] -= corr;
            gat_epilogue<FINAL>(acc8, l32, valid, node, scale, shift, outf, outb);
            return;
        }
    }

    // ======== fallback: sequential full-wave per node (deg>32) ========
    for (int t = 0; t < 2; ++t) {
        int fnode = nodeBase + t;
        if (fnode >= N_NODES) break;
        int fdeg = min(cursor[fnode], CAP);
        int fbeg = fnode * CAP, fend = fbeg + fdeg;
        float4 ad = *(const float4*)(adst + (size_t)fnode * 4);
        float acc8[8];
#pragma unroll
        for (int k = 0; k < 8; ++k) acc8[k] = 0.f;
        float corr;

        if (fdeg <= 64) {
            int s = 0;
            float sc = 0.f;
            float c0 = -3.4e38f, c1 = -3.4e38f, c2 = -3.4e38f, c3 = -3.4e38f;
            if (lane < fdeg) {
                s = csr[fbeg + lane];
                sc = scaleRow[s];
                float4 as = *(const float4*)(asrc + (size_t)s * 4);
                c0 = lrelu(as.x + ad.x); c1 = lrelu(as.y + ad.y);
                c2 = lrelu(as.z + ad.z); c3 = lrelu(as.w + ad.w);
            }
            float m0 = c0, m1 = c1, m2 = c2, m3 = c3;
#pragma unroll
            for (int off = 1; off < 64; off <<= 1) {
                m0 = fmaxf(m0, __shfl_xor(m0, off)); m1 = fmaxf(m1, __shfl_xor(m1, off));
                m2 = fmaxf(m2, __shfl_xor(m2, off)); m3 = fmaxf(m3, __shfl_xor(m3, off));
            }
            float e0 = 0.f, e1 = 0.f, e2 = 0.f, e3 = 0.f;
            if (lane < fdeg) {
                e0 = __expf(c0 - m0); e1 = __expf(c1 - m1);
                e2 = __expf(c2 - m2); e3 = __expf(c3 - m3);
            }
            float s0 = e0, s1 = e1, s2 = e2, s3 = e3;
#pragma unroll
            for (int off = 1; off < 64; off <<= 1) {
                s0 += __shfl_xor(s0, off); s1 += __shfl_xor(s1, off);
                s2 += __shfl_xor(s2, off); s3 += __shfl_xor(s3, off);
            }
            float a0 = e0 / (s0 + 1e-16f) * sc, a1 = e1 / (s1 + 1e-16f) * sc;
            float a2 = e2 / (s2 + 1e-16f) * sc, a3 = e3 / (s3 + 1e-16f) * sc;
            sa[wid][0][lane] = make_int2(s, __float_as_int(a0));
            sa[wid][1][lane] = make_int2(s, __float_as_int(a1));
            sa[wid][2][lane] = make_int2(s, __float_as_int(a2));
            sa[wid][3][lane] = make_int2(s, __float_as_int(a3));
            float t0 = a0, t1 = a1, t2 = a2, t3 = a3;
#pragma unroll
            for (int off = 1; off < 64; off <<= 1) {
                t0 += __shfl_xor(t0, off); t1 += __shfl_xor(t1, off);
                t2 += __shfl_xor(t2, off); t3 += __shfl_xor(t3, off);
            }
            corr = 128.f * (hsel == 0 ? t0 : hsel == 1 ? t1 : hsel == 2 ? t2 : t3);
            __asm__ volatile("s_waitcnt lgkmcnt(0)" ::: "memory");

            const int2* sal = &sa[wid][hsel][0];
            int e = 0;
            for (; e + 1 < fdeg; e += 2) {
                int2 sv = sal[e + g];
                int2 hA = *(const int2*)(h8 + (((unsigned)sv.x << 8) + fo));
                acc_u8(acc8, hA, __int_as_float(sv.y));
            }
            if (e < fdeg) {
                int idx = e + g;
                int2 sv = sal[idx < fdeg ? idx : 0];
                float aA = idx < fdeg ? __int_as_float(sv.y) : 0.f;
                int2 hA = *(const int2*)(h8 + (((unsigned)sv.x << 8) + fo));
                acc_u8(acc8, hA, aA);
            }
#pragma unroll
            for (int k = 0; k < 8; ++k) acc8[k] += __shfl_xor(acc8[k], 32);
        } else {
            float m0 = -3.4e38f, m1 = -3.4e38f, m2 = -3.4e38f, m3 = -3.4e38f;
            for (int e = fbeg + lane; e < fend; e += 64) {
                int s = csr[e];
                float4 as = *(const float4*)(asrc + (size_t)s * 4);
                m0 = fmaxf(m0, lrelu(as.x + ad.x)); m1 = fmaxf(m1, lrelu(as.y + ad.y));
                m2 = fmaxf(m2, lrelu(as.z + ad.z)); m3 = fmaxf(m3, lrelu(as.w + ad.w));
            }
#pragma unroll
            for (int off = 1; off < 64; off <<= 1) {
                m0 = fmaxf(m0, __shfl_xor(m0, off)); m1 = fmaxf(m1, __shfl_xor(m1, off));
                m2 = fmaxf(m2, __shfl_xor(m2, off)); m3 = fmaxf(m3, __shfl_xor(m3, off));
            }
            float s0 = 0.f, s1 = 0.f, s2 = 0.f, s3 = 0.f;
            for (int e = fbeg + lane; e < fend; e += 64) {
                int s = csr[e];
                float4 as = *(const float4*)(asrc + (size_t)s * 4);
                s0 += __expf(lrelu(as.x + ad.x) - m0); s1 += __expf(lrelu(as.y + ad.y) - m1);
                s2 += __expf(lrelu(as.z + ad.z) - m2); s3 += __expf(lrelu(as.w + ad.w) - m3);
            }
#pragma unroll
            for (int off = 1; off < 64; off <<= 1) {
                s0 += __shfl_xor(s0, off); s1 += __shfl_xor(s1, off);
                s2 += __shfl_xor(s2, off); s3 += __shfl_xor(s3, off);
            }
            float mh = (hsel == 0) ? m0 : (hsel == 1) ? m1 : (hsel == 2) ? m2 : m3;
            float rh = (hsel == 0) ? 1.f / (s0 + 1e-16f) : (hsel == 1) ? 1.f / (s1 + 1e-16f)
                     : (hsel == 2) ? 1.f / (s2 + 1e-16f) : 1.f / (s3 + 1e-16f);
            float adh = (hsel == 0) ? ad.x : (hsel == 1) ? ad.y : (hsel == 2) ? ad.z : ad.w;
            float asumL = 0.f;
            for (int e = fbeg; e < fend; ++e) {
                int s = csr[e];
                float ash = asrc[(size_t)s * 4 + hsel];
                float a = __expf(lrelu(ash + adh) - mh) * rh * scaleRow[s];
                asumL += a;
                int2 hv = *(const int2*)(h8 + (((unsigned)s << 8) + fo));
                acc_u8(acc8, hv, a);
            }
            corr = 128.f * asumL;
        }
#pragma unroll
        for (int k = 0; k < 8; ++k) acc8[k] -= corr;
        gat_epilogue<FINAL>(acc8, l32, g == 0, fnode, scale, shift, outf, outb);
    }
}

extern "C" void kernel_launch(void* const* d_in, const int* in_sizes, int n_in,
                              void* d_out, int out_size, void* d_ws, size_t ws_size,
                              hipStream_t stream) {
    (void)in_sizes; (void)n_in; (void)out_size; (void)ws_size;
    const float* x   = (const float*)d_in[0];
    const int*   ei  = (const int*)d_in[1];
    const float* W1  = (const float*)d_in[2];
    const float* as1 = (const float*)d_in[3];
    const float* ad1 = (const float*)d_in[4];
    const float* b1  = (const float*)d_in[5];
    const float* g1  = (const float*)d_in[6];
    const float* be1 = (const float*)d_in[7];
    const float* m1  = (const float*)d_in[8];
    const float* v1  = (const float*)d_in[9];
    const float* W2  = (const float*)d_in[10];
    const float* as2 = (const float*)d_in[11];
    const float* ad2 = (const float*)d_in[12];
    const float* b2  = (const float*)d_in[13];
    const float* g2  = (const float*)d_in[14];
    const float* be2 = (const float*)d_in[15];
    const float* m2  = (const float*)d_in[16];
    const float* v2  = (const float*)d_in[17];

    float* out = (float*)d_out;
    unsigned short* actb = (unsigned short*)d_out;  // layer-1 bf16 acts live in d_out until gemm2

    // ws layout: h8 | scaleRow | xb | asrc | adst | sc/sh x4 | W1T | W2T | cursor | csr
    char* base = (char*)d_ws;
    signed char* h8 = (signed char*)base;          base += (size_t)N_NODES * 256;
    float* scaleRow = (float*)base;                base += (size_t)N_NODES * 4;
    unsigned short* xb  = (unsigned short*)base;   base += (size_t)N_NODES * 128 * 2;
    float* asrc = (float*)base;                    base += (size_t)N_NODES * 4 * 4;
    float* adst = (float*)base;                    base += (size_t)N_NODES * 4 * 4;
    float* sc1 = (float*)base;                     base += 1024;
    float* sh1 = (float*)base;                     base += 1024;
    float* sc2 = (float*)base;                     base += 1024;
    float* sh2 = (float*)base;                     base += 1024;
    unsigned short* W1T = (unsigned short*)base;   base += 256 * 128 * 2;
    unsigned short* W2T = (unsigned short*)base;   base += 256 * 256 * 2;
    int* cursor = (int*)base;                      base += N_NODES * 4;
    int* csr  = (int*)base;                        // N_NODES * CAP * 4 = 19.2 MB

    // 1. cursor = 0 via memset node (graph-capturable; saves a kernel launch)
    hipMemsetAsync(cursor, 0, (size_t)N_NODES * 4, stream);

    // 2. fused setup + CSR scatter, 1:1 block interleave (disjoint resources)
    setup_scatter_kernel<<<SETUP_B + SCAT_B, 256, 0, stream>>>(
        x, xb, W1, W1T, W2, W2T, ei, cursor, csr,
        b1, g1, be1, m1, v1, b2, g2, be2, m2, v2, sc1, sh1, sc2, sh2);

    const int gb = (N_NODES + 63) / 64;              // 782 gemm blocks (64-row tiles)
    const int nb = (N_NODES + 7) / 8;                // gather: 8 nodes per block

    // 3-4. layer 1
    gemm_fused_kernel<128><<<gb, 256, 0, stream>>>(xb, W1T, as1, ad1, h8, scaleRow,
                                                   asrc, adst, N_NODES);
    gat_gather_kernel<false><<<nb, 256, 0, stream>>>(cursor, csr, asrc, adst, scaleRow, h8,
                                                     sc1, sh1, nullptr, actb);

    // 5-6. layer 2
    gemm_fused_kernel<256><<<gb, 256, 0, stream>>>(actb, W2T, as2, ad2, h8, scaleRow,
                                                   asrc, adst, N_NODES);
    gat_gather_kernel<true><<<nb, 256, 0, stream>>>(cursor, csr, asrc, adst, scaleRow, h8,
                                                    sc2, sh2, out, nullptr);
}

// Round 14
// 289.568 us; speedup vs baseline: 1.0452x; 1.0452x over previous
//
// v15 — dispatch-count attack. r13 null + r6's MfmaUtil=1.3% anchor -> gemms are
// barrier/latency floors (~27/33us) and ~75us sits in inter-dispatch overhead
// (~12us x 6). Plan: (1) prep kernel = cursor-zero + W1T/W2T + BN (replaces
// memset); (2) gemm1 fused INTO scatter with 1:1 interleave (r7 technique),
// staging A directly from f32 x via the same f2b -> bit-identical, xb pass
// deleted; (3) gemm2 = r12 padded form. 6 -> 5 dispatches.
#include <hip/hip_runtime.h>
#include <hip/hip_bf16.h>
#include <cstdint>

#define N_NODES 50000
#define N_EDGES 800000
#define ET_EDGES (N_EDGES + N_NODES)   // with self-loops
#define FDIM 256
#define BN_EPS 1e-5f
#define CAP 96                         // fixed CSR slots per node; P(deg>96)~0 for Poisson(17)

typedef short bf16x8 __attribute__((ext_vector_type(8)));   // 8 bf16 = 4 VGPRs
typedef float f32x4 __attribute__((ext_vector_type(4)));

__device__ __forceinline__ float lrelu(float x) { return x >= 0.f ? x : 0.2f * x; }
__device__ __forceinline__ unsigned short f2b(float f) {   // RNE
    unsigned int u = __float_as_uint(f);
    u += 0x7fffu + ((u >> 16) & 1u);
    return (unsigned short)(u >> 16);
}

// u8 (biased int8: q+128) dequant-accumulate: 8 features from an int2, coefficient c.
__device__ __forceinline__ void acc_u8(float acc8[8], int2 p, float c) {
    unsigned px = (unsigned)p.x, py = (unsigned)p.y;
#pragma unroll
    for (int k = 0; k < 4; ++k)
        acc8[k] = fmaf((float)((unsigned char)(px >> (8 * k))), c, acc8[k]);
#pragma unroll
    for (int k = 0; k < 4; ++k)
        acc8[k + 4] = fmaf((float)((unsigned char)(py >> (8 * k))), c, acc8[k + 4]);
}

// ---------------- prep: cursor=0 | W1^T | W2^T | BN prep (replaces memset) ----------
#define PB_Z  196               // ceil(50000/256)
#define PB_W1 128               // 256*128 / 256
#define PB_W2 256               // 256*256 / 256
__global__ __launch_bounds__(256) void prep_kernel(
        const float* __restrict__ W1, unsigned short* __restrict__ W1T,
        const float* __restrict__ W2, unsigned short* __restrict__ W2T,
        int* __restrict__ cursor,
        const float* __restrict__ b1, const float* __restrict__ g1,
        const float* __restrict__ be1, const float* __restrict__ m1,
        const float* __restrict__ v1,
        const float* __restrict__ b2, const float* __restrict__ g2,
        const float* __restrict__ be2, const float* __restrict__ m2,
        const float* __restrict__ v2,
        float* sc1, float* sh1, float* sc2, float* sh2) {
    int b = blockIdx.x, tid = threadIdx.x;
    if (b < PB_Z) {
        int i = b * 256 + tid;
        if (i < N_NODES) cursor[i] = 0;
    } else if (b < PB_Z + PB_W1) {
        int t = (b - PB_Z) * 256 + tid;              // over 256*128
        int n = t >> 7, k = t & 127;
        W1T[t] = f2b(W1[(size_t)k * 256 + n]);
    } else if (b < PB_Z + PB_W1 + PB_W2) {
        int t = (b - PB_Z - PB_W1) * 256 + tid;      // over 256*256
        int n = t >> 8, k = t & 255;
        W2T[t] = f2b(W2[(size_t)k * 256 + n]);
    } else {
        int f = tid;
        float s1 = rsqrtf(v1[f] + BN_EPS) * g1[f];
        sc1[f] = s1;
        sh1[f] = (b1[f] - m1[f]) * s1 + be1[f];
        float s2 = rsqrtf(v2[f] + BN_EPS) * g2[f];
        sc2[f] = s2;
        sh2[f] = (b2[f] - m2[f]) * s2 + be2[f];
    }
}

// ------- fused scatter + layer-1 GEMM, 1:1 interleaved blocks -------
// Scatter: 1 edge/thread (atomic-unit-bound, rate-limited not wave-limited).
// GEMM1: 64x256 tile, K=128, A staged DIRECTLY from f32 x via f2b (bit-identical
// to the old xb path); B = W1T bf16. u8-quant + fused adot epilogue (r12 form).
#define SG_GEMM 782             // ceil(50000/64)
#define SG_SCAT 3321            // ceil(850000/256)
#define SG_MIX  (2 * SG_GEMM)   // first 1564 blocks alternate scatter/gemm
__global__ __launch_bounds__(256) void scat_gemm1_kernel(
        const int* __restrict__ ei, int* __restrict__ cursor, int* __restrict__ csr,
        const float* __restrict__ x,
        const unsigned short* __restrict__ BT,
        const float* __restrict__ a_src, const float* __restrict__ a_dst,
        signed char* __restrict__ H8, float* __restrict__ scaleRow,
        float* __restrict__ asrc, float* __restrict__ adst, int M) {
    constexpr int K = 128;
    constexpr int BK = 64;
    __shared__ unsigned short As[64][BK + 8];    // row stride 144 B
    __shared__ unsigned short Bs[256][BK + 8];
    __shared__ int amaxL[64];
    const int tid = threadIdx.x;
    const int b = blockIdx.x;

    int gemmIdx = -1, scatIdx = 0;
    if (b < SG_MIX) { if (b & 1) gemmIdx = b >> 1; else scatIdx = b >> 1; }
    else scatIdx = b - SG_GEMM;

    if (gemmIdx < 0) {
        // ---- scatter block: 1 edge/thread ----
        int e = scatIdx * 256 + tid;
        if (e < ET_EDGES) {
            int s, d;
            if (e < N_EDGES) { s = ei[e]; d = ei[N_EDGES + e]; }
            else             { s = d = e - N_EDGES; }
            int pos = atomicAdd(&cursor[d], 1);
            if (pos < CAP) csr[d * CAP + pos] = s;
        }
        return;
    }

    // ---- gemm1 block ----
    const int lane = tid & 63;
    const int w = tid >> 6;          // 0..3
    const int bm = gemmIdx * 64;
    const int wc = w * 64;
    const int hd = w;
    if (tid < 64) amaxL[tid] = 0;

    f32x4 acc[4][4];
#pragma unroll
    for (int i = 0; i < 4; ++i)
#pragma unroll
        for (int j = 0; j < 4; ++j) acc[i][j] = (f32x4){0.f, 0.f, 0.f, 0.f};

    const int srow = tid >> 3;       // 0..31
    const int skc = (tid & 7) * 8;

    for (int k0 = 0; k0 < K; k0 += BK) {
#pragma unroll
        for (int i = 0; i < 2; ++i) {            // A: 64 rows from f32 x, cvt in-reg
            int row = i * 32 + srow;
            int ar = bm + row; if (ar >= M) ar = M - 1;
            const float* xp = x + (size_t)ar * K + k0 + skc;
            float4 v0 = *(const float4*)xp;
            float4 v1 = *(const float4*)(xp + 4);
            bf16x8 o;
            o[0] = (short)f2b(v0.x); o[1] = (short)f2b(v0.y);
            o[2] = (short)f2b(v0.z); o[3] = (short)f2b(v0.w);
            o[4] = (short)f2b(v1.x); o[5] = (short)f2b(v1.y);
            o[6] = (short)f2b(v1.z); o[7] = (short)f2b(v1.w);
            *(bf16x8*)&As[row][skc] = o;
        }
#pragma unroll
        for (int i = 0; i < 8; ++i) {            // B: 256 rows, bf16
            int row = i * 32 + srow;
            *(bf16x8*)&Bs[row][skc] = *(const bf16x8*)(BT + (size_t)row * K + k0 + skc);
        }
        __syncthreads();
#pragma unroll
        for (int ks = 0; ks < BK; ks += 32) {
            const int kk = ks + (lane >> 4) * 8;
            bf16x8 af[4], bfr[4];
#pragma unroll
            for (int i = 0; i < 4; ++i) {
                af[i]  = *(const bf16x8*)&As[i * 16 + (lane & 15)][kk];
                bfr[i] = *(const bf16x8*)&Bs[wc + i * 16 + (lane & 15)][kk];
            }
#pragma unroll
            for (int i = 0; i < 4; ++i)
#pragma unroll
                for (int j = 0; j < 4; ++j)
                    acc[i][j] = __builtin_amdgcn_mfma_f32_16x16x32_bf16(af[i], bfr[j], acc[i][j], 0, 0, 0);
        }
        __syncthreads();
    }

    const int q = lane >> 4, c16 = lane & 15;
#pragma unroll
    for (int i = 0; i < 4; ++i) {
#pragma unroll
        for (int r = 0; r < 4; ++r) {
            float a = fmaxf(fmaxf(fabsf(acc[i][0][r]), fabsf(acc[i][1][r])),
                            fmaxf(fabsf(acc[i][2][r]), fabsf(acc[i][3][r])));
#pragma unroll
            for (int off = 1; off < 16; off <<= 1) a = fmaxf(a, __shfl_xor(a, off));
            if (c16 == 0) atomicMax(&amaxL[i * 16 + q * 4 + r], __float_as_int(a));
        }
    }
    __syncthreads();

    float asv[4], adv[4];
#pragma unroll
    for (int j = 0; j < 4; ++j) {
        int c = j * 16 + c16;
        asv[j] = a_src[hd * 64 + c];
        adv[j] = a_dst[hd * 64 + c];
    }
#pragma unroll
    for (int i = 0; i < 4; ++i) {
#pragma unroll
        for (int r = 0; r < 4; ++r) {
            int lrow = i * 16 + q * 4 + r;
            int gr = bm + lrow;
            float amax = __int_as_float(amaxL[lrow]);
            float rcpS = amax > 1e-20f ? 127.f / amax : 0.f;
            if (gr < M) {
#pragma unroll
                for (int j = 0; j < 4; ++j) {
                    int qv = (int)rintf(acc[i][j][r] * rcpS);
                    H8[(size_t)gr * 256 + wc + j * 16 + c16] =
                        (signed char)(unsigned char)(qv + 128);
                }
                if (c16 == 0 && w == 0) scaleRow[gr] = amax * (1.f / 127.f);
            }
            float p_s = acc[i][0][r] * asv[0] + acc[i][1][r] * asv[1]
                      + acc[i][2][r] * asv[2] + acc[i][3][r] * asv[3];
            float p_d = acc[i][0][r] * adv[0] + acc[i][1][r] * adv[1]
                      + acc[i][2][r] * adv[2] + acc[i][3][r] * adv[3];
#pragma unroll
            for (int off = 1; off < 16; off <<= 1) {
                p_s += __shfl_xor(p_s, off);
                p_d += __shfl_xor(p_d, off);
            }
            if (c16 == 0 && gr < M) {
                asrc[(size_t)gr * 4 + hd] = p_s;
                adst[(size_t)gr * 4 + hd] = p_d;
            }
        }
    }
}

// ------- bf16 MFMA GEMM 64x256 tile (r12 form) + u8-quant + fused adot -------
template <int K>
__global__ __launch_bounds__(256) void gemm_fused_kernel(
        const unsigned short* __restrict__ A,
        const unsigned short* __restrict__ BT,
        const float* __restrict__ a_src, const float* __restrict__ a_dst,
        signed char* __restrict__ H8, float* __restrict__ scaleRow,
        float* __restrict__ asrc, float* __restrict__ adst, int M) {
    constexpr int BK = 64;
    __shared__ unsigned short As[64][BK + 8];    // row stride 144 B
    __shared__ unsigned short Bs[256][BK + 8];
    __shared__ int amaxL[64];
    const int tid = threadIdx.x;
    const int lane = tid & 63;
    const int w = tid >> 6;          // 0..3
    const int bm = blockIdx.x * 64;
    const int wc = w * 64;
    const int hd = w;
    if (tid < 64) amaxL[tid] = 0;

    f32x4 acc[4][4];
#pragma unroll
    for (int i = 0; i < 4; ++i)
#pragma unroll
        for (int j = 0; j < 4; ++j) acc[i][j] = (f32x4){0.f, 0.f, 0.f, 0.f};

    const int srow = tid >> 3;       // 0..31
    const int skc = (tid & 7) * 8;

    for (int k0 = 0; k0 < K; k0 += BK) {
#pragma unroll
        for (int i = 0; i < 2; ++i) {            // A: 64 rows, 32/pass
            int row = i * 32 + srow;
            int ar = bm + row; if (ar >= M) ar = M - 1;
            *(bf16x8*)&As[row][skc] = *(const bf16x8*)(A + (size_t)ar * K + k0 + skc);
        }
#pragma unroll
        for (int i = 0; i < 8; ++i) {            // B: 256 rows, 32/pass
            int row = i * 32 + srow;
            *(bf16x8*)&Bs[row][skc] = *(const bf16x8*)(BT + (size_t)row * K + k0 + skc);
        }
        __syncthreads();
#pragma unroll
        for (int ks = 0; ks < BK; ks += 32) {
            const int kk = ks + (lane >> 4) * 8;
            bf16x8 af[4], bfr[4];
#pragma unroll
            for (int i = 0; i < 4; ++i) {
                af[i]  = *(const bf16x8*)&As[i * 16 + (lane & 15)][kk];
                bfr[i] = *(const bf16x8*)&Bs[wc + i * 16 + (lane & 15)][kk];
            }
#pragma unroll
            for (int i = 0; i < 4; ++i)
#pragma unroll
                for (int j = 0; j < 4; ++j)
                    acc[i][j] = __builtin_amdgcn_mfma_f32_16x16x32_bf16(af[i], bfr[j], acc[i][j], 0, 0, 0);
        }
        __syncthreads();
    }

    const int q = lane >> 4, c16 = lane & 15;
#pragma unroll
    for (int i = 0; i < 4; ++i) {
#pragma unroll
        for (int r = 0; r < 4; ++r) {
            float a = fmaxf(fmaxf(fabsf(acc[i][0][r]), fabsf(acc[i][1][r])),
                            fmaxf(fabsf(acc[i][2][r]), fabsf(acc[i][3][r])));
#pragma unroll
            for (int off = 1; off < 16; off <<= 1) a = fmaxf(a, __shfl_xor(a, off));
            if (c16 == 0) atomicMax(&amaxL[i * 16 + q * 4 + r], __float_as_int(a));
        }
    }
    __syncthreads();

    float asv[4], adv[4];
#pragma unroll
    for (int j = 0; j < 4; ++j) {
        int c = j * 16 + c16;
        asv[j] = a_src[hd * 64 + c];
        adv[j] = a_dst[hd * 64 + c];
    }
#pragma unroll
    for (int i = 0; i < 4; ++i) {
#pragma unroll
        for (int r = 0; r < 4; ++r) {
            int lrow = i * 16 + q * 4 + r;
            int gr = bm + lrow;
            float amax = __int_as_float(amaxL[lrow]);
            float rcpS = amax > 1e-20f ? 127.f / amax : 0.f;
            if (gr < M) {
#pragma unroll
                for (int j = 0; j < 4; ++j) {
                    int qv = (int)rintf(acc[i][j][r] * rcpS);
                    H8[(size_t)gr * 256 + wc + j * 16 + c16] =
                        (signed char)(unsigned char)(qv + 128);
                }
                if (c16 == 0 && w == 0) scaleRow[gr] = amax * (1.f / 127.f);
            }
            float p_s = acc[i][0][r] * asv[0] + acc[i][1][r] * asv[1]
                      + acc[i][2][r] * asv[2] + acc[i][3][r] * asv[3];
            float p_d = acc[i][0][r] * adv[0] + acc[i][1][r] * adv[1]
                      + acc[i][2][r] * adv[2] + acc[i][3][r] * adv[3];
#pragma unroll
            for (int off = 1; off < 16; off <<= 1) {
                p_s += __shfl_xor(p_s, off);
                p_d += __shfl_xor(p_d, off);
            }
            if (c16 == 0 && gr < M) {
                asrc[(size_t)gr * 4 + hd] = p_s;
                adst[(size_t)gr * 4 + hd] = p_d;
            }
        }
    }
}

// ---- shared epilogue: BN + ReLU (+ log_softmax over a 32-lane group) ----
template <bool FINAL>
__device__ __forceinline__ void gat_epilogue(const float acc8[8], int fl, bool doStore,
                                             int node, const float* __restrict__ scale,
                                             const float* __restrict__ shift,
                                             float* __restrict__ outf,
                                             unsigned short* __restrict__ outb) {
    float4 scA = ((const float4*)scale)[fl * 2], scB = ((const float4*)scale)[fl * 2 + 1];
    float4 shA = ((const float4*)shift)[fl * 2], shB = ((const float4*)shift)[fl * 2 + 1];
    float t[8];
    t[0] = fmaxf(fmaf(acc8[0], scA.x, shA.x), 0.f);
    t[1] = fmaxf(fmaf(acc8[1], scA.y, shA.y), 0.f);
    t[2] = fmaxf(fmaf(acc8[2], scA.z, shA.z), 0.f);
    t[3] = fmaxf(fmaf(acc8[3], scA.w, shA.w), 0.f);
    t[4] = fmaxf(fmaf(acc8[4], scB.x, shB.x), 0.f);
    t[5] = fmaxf(fmaf(acc8[5], scB.y, shB.y), 0.f);
    t[6] = fmaxf(fmaf(acc8[6], scB.z, shB.z), 0.f);
    t[7] = fmaxf(fmaf(acc8[7], scB.w, shB.w), 0.f);
    if (FINAL) {
        float m = t[0];
#pragma unroll
        for (int k = 1; k < 8; ++k) m = fmaxf(m, t[k]);
#pragma unroll
        for (int off = 1; off < 32; off <<= 1) m = fmaxf(m, __shfl_xor(m, off));
        float es = 0.f;
#pragma unroll
        for (int k = 0; k < 8; ++k) es += __expf(t[k] - m);
#pragma unroll
        for (int off = 1; off < 32; off <<= 1) es += __shfl_xor(es, off);
        float lse = m + logf(es);
        if (doStore) {
            float* p = outf + (size_t)node * 256 + fl * 8;
            *(float4*)p = make_float4(t[0] - lse, t[1] - lse, t[2] - lse, t[3] - lse);
            *(float4*)(p + 4) = make_float4(t[4] - lse, t[5] - lse, t[6] - lse, t[7] - lse);
        }
    } else {
        if (doStore) {
            bf16x8 ob;
#pragma unroll
            for (int k = 0; k < 8; ++k) ob[k] = (short)f2b(t[k]);
            *(bf16x8*)(outb + (size_t)node * 256 + fl * 8) = ob;
        }
    }
}

// ------- fused gather (r7 exact): one-shot 8-node blocks, u8 payload + cvt_ubyte
//         dequant, packed {src,alpha} ds_read_b64, 2 nodes/wave, 8 edges in flight -------
template <bool FINAL>
__global__ __launch_bounds__(256) void gat_gather_kernel(
        const int* __restrict__ cursor,
        const int* __restrict__ csr,
        const float* __restrict__ asrc,
        const float* __restrict__ adst,
        const float* __restrict__ scaleRow,
        const signed char* __restrict__ h8,
        const float* __restrict__ scale,
        const float* __restrict__ shift,
        float* __restrict__ outf,
        unsigned short* __restrict__ outb) {
    // [wave][head][slot] = {src, alpha*scale}; 65 pad -> head arrays 2 banks apart
    __shared__ int2 sa[4][4][65];

    const int wid = threadIdx.x >> 6;
    const int lane = threadIdx.x & 63;
    const int g = lane >> 5, l32 = lane & 31;
    const int hsel = l32 >> 3;
    const unsigned fo = (unsigned)(l32 << 3);   // byte offset of this lane's 8 features

    const int nodeBase = blockIdx.x * 8 + wid * 2;
    if (nodeBase >= N_NODES) return;

    {
        int node = nodeBase + g;
        bool valid = node < N_NODES;
        int nodeC = valid ? node : N_NODES - 1;
        int deg = valid ? min(cursor[nodeC], CAP) : 0;
        int beg = nodeC * CAP;
        int dmax = max(deg, __shfl_xor(deg, 32));

        if (dmax <= 32) {
            // ======== fast path: 32-lane group per node ========
            float4 ad = *(const float4*)(adst + (size_t)nodeC * 4);
            int s = 0;
            float sc = 0.f;
            float c0 = -3.4e38f, c1 = -3.4e38f, c2 = -3.4e38f, c3 = -3.4e38f;
            if (l32 < deg) {
                s = csr[beg + l32];
                sc = scaleRow[s];
                float4 as = *(const float4*)(asrc + (size_t)s * 4);
                c0 = lrelu(as.x + ad.x); c1 = lrelu(as.y + ad.y);
                c2 = lrelu(as.z + ad.z); c3 = lrelu(as.w + ad.w);
            }
            float m0 = c0, m1 = c1, m2 = c2, m3 = c3;
#pragma unroll
            for (int off = 1; off < 32; off <<= 1) {
                m0 = fmaxf(m0, __shfl_xor(m0, off)); m1 = fmaxf(m1, __shfl_xor(m1, off));
                m2 = fmaxf(m2, __shfl_xor(m2, off)); m3 = fmaxf(m3, __shfl_xor(m3, off));
            }
            float e0 = 0.f, e1 = 0.f, e2 = 0.f, e3 = 0.f;
            if (l32 < deg) {
                e0 = __expf(c0 - m0); e1 = __expf(c1 - m1);
                e2 = __expf(c2 - m2); e3 = __expf(c3 - m3);
            }
            float s0 = e0, s1 = e1, s2 = e2, s3 = e3;
#pragma unroll
            for (int off = 1; off < 32; off <<= 1) {
                s0 += __shfl_xor(s0, off); s1 += __shfl_xor(s1, off);
                s2 += __shfl_xor(s2, off); s3 += __shfl_xor(s3, off);
            }
            float a0 = e0 / (s0 + 1e-16f) * sc, a1 = e1 / (s1 + 1e-16f) * sc;
            float a2 = e2 / (s2 + 1e-16f) * sc, a3 = e3 / (s3 + 1e-16f) * sc;
            sa[wid][0][lane] = make_int2(s, __float_as_int(a0));   // slot == lane
            sa[wid][1][lane] = make_int2(s, __float_as_int(a1));
            sa[wid][2][lane] = make_int2(s, __float_as_int(a2));
            sa[wid][3][lane] = make_int2(s, __float_as_int(a3));
            // asum = sum(alpha*scale) per head, for the u8 bias correction
            float t0 = a0, t1 = a1, t2 = a2, t3 = a3;
#pragma unroll
            for (int off = 1; off < 32; off <<= 1) {
                t0 += __shfl_xor(t0, off); t1 += __shfl_xor(t1, off);
                t2 += __shfl_xor(t2, off); t3 += __shfl_xor(t3, off);
            }
            float corr = 128.f * (hsel == 0 ? t0 : hsel == 1 ? t1 : hsel == 2 ? t2 : t3);
            __asm__ volatile("s_waitcnt lgkmcnt(0)" ::: "memory");  // wave-local LDS RAW

            const int2* sal = &sa[wid][hsel][g * 32];
            float acc8[8];
#pragma unroll
            for (int k = 0; k < 8; ++k) acc8[k] = 0.f;

            int e = 0;
            for (; e + 7 < deg; e += 8) {               // 8 loads in flight
                int2 sv[8]; int2 hv[8];
#pragma unroll
                for (int u = 0; u < 8; ++u) sv[u] = sal[e + u];    // ds_read_b64
#pragma unroll
                for (int u = 0; u < 8; ++u)
                    hv[u] = *(const int2*)(h8 + (((unsigned)sv[u].x << 8) + fo));
#pragma unroll
                for (int u = 0; u < 8; ++u) acc_u8(acc8, hv[u], __int_as_float(sv[u].y));
            }
            for (; e + 3 < deg; e += 4) {
                int2 sv[4]; int2 hv[4];
#pragma unroll
                for (int u = 0; u < 4; ++u) sv[u] = sal[e + u];
#pragma unroll
                for (int u = 0; u < 4; ++u)
                    hv[u] = *(const int2*)(h8 + (((unsigned)sv[u].x << 8) + fo));
#pragma unroll
                for (int u = 0; u < 4; ++u) acc_u8(acc8, hv[u], __int_as_float(sv[u].y));
            }
            for (; e < deg; ++e) {
                int2 sv = sal[e];
                int2 hA = *(const int2*)(h8 + (((unsigned)sv.x << 8) + fo));
                acc_u8(acc8, hA, __int_as_float(sv.y));
            }
#pragma unroll
            for (int k = 0; k < 8; ++k) acc8[k] -= corr;
            gat_epilogue<FINAL>(acc8, l32, valid, node, scale, shift, outf, outb);
            return;
        }
    }

    // ======== fallback: sequential full-wave per node (deg>32) ========
    for (int t = 0; t < 2; ++t) {
        int fnode = nodeBase + t;
        if (fnode >= N_NODES) break;
        int fdeg = min(cursor[fnode], CAP);
        int fbeg = fnode * CAP, fend = fbeg + fdeg;
        float4 ad = *(const float4*)(adst + (size_t)fnode * 4);
        float acc8[8];
#pragma unroll
        for (int k = 0; k < 8; ++k) acc8[k] = 0.f;
        float corr;

        if (fdeg <= 64) {
            int s = 0;
            float sc = 0.f;
            float c0 = -3.4e38f, c1 = -3.4e38f, c2 = -3.4e38f, c3 = -3.4e38f;
            if (lane < fdeg) {
                s = csr[fbeg + lane];
                sc = scaleRow[s];
                float4 as = *(const float4*)(asrc + (size_t)s * 4);
                c0 = lrelu(as.x + ad.x); c1 = lrelu(as.y + ad.y);
                c2 = lrelu(as.z + ad.z); c3 = lrelu(as.w + ad.w);
            }
            float m0 = c0, m1 = c1, m2 = c2, m3 = c3;
#pragma unroll
            for (int off = 1; off < 64; off <<= 1) {
                m0 = fmaxf(m0, __shfl_xor(m0, off)); m1 = fmaxf(m1, __shfl_xor(m1, off));
                m2 = fmaxf(m2, __shfl_xor(m2, off)); m3 = fmaxf(m3, __shfl_xor(m3, off));
            }
            float e0 = 0.f, e1 = 0.f, e2 = 0.f, e3 = 0.f;
            if (lane < fdeg) {
                e0 = __expf(c0 - m0); e1 = __expf(c1 - m1);
                e2 = __expf(c2 - m2); e3 = __expf(c3 - m3);
            }
            float s0 = e0, s1 = e1, s2 = e2, s3 = e3;
#pragma unroll
            for (int off = 1; off < 64; off <<= 1) {
                s0 += __shfl_xor(s0, off); s1 += __shfl_xor(s1, off);
                s2 += __shfl_xor(s2, off); s3 += __shfl_xor(s3, off);
            }
            float a0 = e0 / (s0 + 1e-16f) * sc, a1 = e1 / (s1 + 1e-16f) * sc;
            float a2 = e2 / (s2 + 1e-16f) * sc, a3 = e3 / (s3 + 1e-16f) * sc;
            sa[wid][0][lane] = make_int2(s, __float_as_int(a0));
            sa[wid][1][lane] = make_int2(s, __float_as_int(a1));
            sa[wid][2][lane] = make_int2(s, __float_as_int(a2));
            sa[wid][3][lane] = make_int2(s, __float_as_int(a3));
            float t0 = a0, t1 = a1, t2 = a2, t3 = a3;
#pragma unroll
            for (int off = 1; off < 64; off <<= 1) {
                t0 += __shfl_xor(t0, off); t1 += __shfl_xor(t1, off);
                t2 += __shfl_xor(t2, off); t3 += __shfl_xor(t3, off);
            }
            corr = 128.f * (hsel == 0 ? t0 : hsel == 1 ? t1 : hsel == 2 ? t2 : t3);
            __asm__ volatile("s_waitcnt lgkmcnt(0)" ::: "memory");

            const int2* sal = &sa[wid][hsel][0];
            int e = 0;
            for (; e + 1 < fdeg; e += 2) {
                int2 sv = sal[e + g];
                int2 hA = *(const int2*)(h8 + (((unsigned)sv.x << 8) + fo));
                acc_u8(acc8, hA, __int_as_float(sv.y));
            }
            if (e < fdeg) {
                int idx = e + g;
                int2 sv = sal[idx < fdeg ? idx : 0];
                float aA = idx < fdeg ? __int_as_float(sv.y) : 0.f;
                int2 hA = *(const int2*)(h8 + (((unsigned)sv.x << 8) + fo));
                acc_u8(acc8, hA, aA);
            }
#pragma unroll
            for (int k = 0; k < 8; ++k) acc8[k] += __shfl_xor(acc8[k], 32);
        } else {
            float m0 = -3.4e38f, m1 = -3.4e38f, m2 = -3.4e38f, m3 = -3.4e38f;
            for (int e = fbeg + lane; e < fend; e += 64) {
                int s = csr[e];
                float4 as = *(const float4*)(asrc + (size_t)s * 4);
                m0 = fmaxf(m0, lrelu(as.x + ad.x)); m1 = fmaxf(m1, lrelu(as.y + ad.y));
                m2 = fmaxf(m2, lrelu(as.z + ad.z)); m3 = fmaxf(m3, lrelu(as.w + ad.w));
            }
#pragma unroll
            for (int off = 1; off < 64; off <<= 1) {
                m0 = fmaxf(m0, __shfl_xor(m0, off)); m1 = fmaxf(m1, __shfl_xor(m1, off));
                m2 = fmaxf(m2, __shfl_xor(m2, off)); m3 = fmaxf(m3, __shfl_xor(m3, off));
            }
            float s0 = 0.f, s1 = 0.f, s2 = 0.f, s3 = 0.f;
            for (int e = fbeg + lane; e < fend; e += 64) {
                int s = csr[e];
                float4 as = *(const float4*)(asrc + (size_t)s * 4);
                s0 += __expf(lrelu(as.x + ad.x) - m0); s1 += __expf(lrelu(as.y + ad.y) - m1);
                s2 += __expf(lrelu(as.z + ad.z) - m2); s3 += __expf(lrelu(as.w + ad.w) - m3);
            }
#pragma unroll
            for (int off = 1; off < 64; off <<= 1) {
                s0 += __shfl_xor(s0, off); s1 += __shfl_xor(s1, off);
                s2 += __shfl_xor(s2, off); s3 += __shfl_xor(s3, off);
            }
            float mh = (hsel == 0) ? m0 : (hsel == 1) ? m1 : (hsel == 2) ? m2 : m3;
            float rh = (hsel == 0) ? 1.f / (s0 + 1e-16f) : (hsel == 1) ? 1.f / (s1 + 1e-16f)
                     : (hsel == 2) ? 1.f / (s2 + 1e-16f) : 1.f / (s3 + 1e-16f);
            float adh = (hsel == 0) ? ad.x : (hsel == 1) ? ad.y : (hsel == 2) ? ad.z : ad.w;
            float asumL = 0.f;
            for (int e = fbeg; e < fend; ++e) {
                int s = csr[e];
                float ash = asrc[(size_t)s * 4 + hsel];
                float a = __expf(lrelu(ash + adh) - mh) * rh * scaleRow[s];
                asumL += a;
                int2 hv = *(const int2*)(h8 + (((unsigned)s << 8) + fo));
                acc_u8(acc8, hv, a);
            }
            corr = 128.f * asumL;
        }
#pragma unroll
        for (int k = 0; k < 8; ++k) acc8[k] -= corr;
        gat_epilogue<FINAL>(acc8, l32, g == 0, fnode, scale, shift, outf, outb);
    }
}

extern "C" void kernel_launch(void* const* d_in, const int* in_sizes, int n_in,
                              void* d_out, int out_size, void* d_ws, size_t ws_size,
                              hipStream_t stream) {
    (void)in_sizes; (void)n_in; (void)out_size; (void)ws_size;
    const float* x   = (const float*)d_in[0];
    const int*   ei  = (const int*)d_in[1];
    const float* W1  = (const float*)d_in[2];
    const float* as1 = (const float*)d_in[3];
    const float* ad1 = (const float*)d_in[4];
    const float* b1  = (const float*)d_in[5];
    const float* g1  = (const float*)d_in[6];
    const float* be1 = (const float*)d_in[7];
    const float* m1  = (const float*)d_in[8];
    const float* v1  = (const float*)d_in[9];
    const float* W2  = (const float*)d_in[10];
    const float* as2 = (const float*)d_in[11];
    const float* ad2 = (const float*)d_in[12];
    const float* b2  = (const float*)d_in[13];
    const float* g2  = (const float*)d_in[14];
    const float* be2 = (const float*)d_in[15];
    const float* m2  = (const float*)d_in[16];
    const float* v2  = (const float*)d_in[17];

    float* out = (float*)d_out;
    unsigned short* actb = (unsigned short*)d_out;  // layer-1 bf16 acts live in d_out until gemm2

    // ws layout: h8 | scaleRow | (xb: unused, kept for layout) | asrc | adst |
    //            sc/sh x4 | W1T | W2T | cursor | csr
    char* base = (char*)d_ws;
    signed char* h8 = (signed char*)base;          base += (size_t)N_NODES * 256;
    float* scaleRow = (float*)base;                base += (size_t)N_NODES * 4;
    base += (size_t)N_NODES * 128 * 2;             // xb slot (unused since v15)
    float* asrc = (float*)base;                    base += (size_t)N_NODES * 4 * 4;
    float* adst = (float*)base;                    base += (size_t)N_NODES * 4 * 4;
    float* sc1 = (float*)base;                     base += 1024;
    float* sh1 = (float*)base;                     base += 1024;
    float* sc2 = (float*)base;                     base += 1024;
    float* sh2 = (float*)base;                     base += 1024;
    unsigned short* W1T = (unsigned short*)base;   base += 256 * 128 * 2;
    unsigned short* W2T = (unsigned short*)base;   base += 256 * 256 * 2;
    int* cursor = (int*)base;                      base += N_NODES * 4;
    int* csr  = (int*)base;                        // N_NODES * CAP * 4 = 19.2 MB

    // 1. prep: cursor=0, W transposes, BN prep
    prep_kernel<<<PB_Z + PB_W1 + PB_W2 + 1, 256, 0, stream>>>(
        W1, W1T, W2, W2T, cursor,
        b1, g1, be1, m1, v1, b2, g2, be2, m2, v2, sc1, sh1, sc2, sh2);

    const int nb = (N_NODES + 7) / 8;                // gather: 8 nodes per block
    const int gb = (N_NODES + 63) / 64;              // 782 gemm blocks (64-row tiles)

    // 2. fused CSR scatter + layer-1 GEMM (1:1 interleaved; gemm1 reads x directly)
    scat_gemm1_kernel<<<SG_SCAT + SG_GEMM, 256, 0, stream>>>(
        ei, cursor, csr, x, W1T, as1, ad1, h8, scaleRow, asrc, adst, N_NODES);

    // 3. layer-1 gather
    gat_gather_kernel<false><<<nb, 256, 0, stream>>>(cursor, csr, asrc, adst, scaleRow, h8,
                                                     sc1, sh1, nullptr, actb);

    // 4. layer-2 GEMM
    gemm_fused_kernel<256><<<gb, 256, 0, stream>>>(actb, W2T, as2, ad2, h8, scaleRow,
                                                   asrc, adst, N_NODES);

    // 5. layer-2 gather
    gat_gather_kernel<true><<<nb, 256, 0, stream>>>(cursor, csr, asrc, adst, scaleRow, h8,
                                                    sc2, sh2, out, nullptr);
}